// Round 8
// baseline (362.671 us; speedup 1.0000x reference)
//
#include <hip/hip_runtime.h>
#include <math.h>

#define NN 8
#define CC 64
#define HH 256
#define WW 256
#define K2 9
#define OC 72          // G*k2
#define BN_EPS 1e-5f
#define NBLK 1024      // 2 blocks per (n,c) plane; 4 blocks/CU * 256 CU = capacity

typedef float f4 __attribute__((ext_vector_type(4)));

// Single fused kernel, self-affine: block b pools rows [half*128,+128) of plane
// (b>>1), publishes its partial with a store-only flag protocol (NO atomic RMWs
// -- R3 measured ~195ns per serialized cross-XCD RMW; plain release-stores
// don't chain), spins for its image's 128 flags, rebuilds pooled+taps in-block,
// then convolves the SAME 128 rows it just read -- those lines are partially
// resident in its own XCD's L2, so conv reads avoid the contended fabric path
// (R6 analysis: main is pinned at ~75us by a ~3.5 TB/s mixed L3-read+HBM-write
// aggregate ceiling; L2 self-hits are the only way under it).
// Deadlock-free: grid == co-residency capacity (VGPR<=128 by launch_bounds,
// LDS ~1KiB -> 4 blocks/CU), and every block publishes before it ever spins.
__global__ __launch_bounds__(256, 4) void fused_kernel(
    const float* __restrict__ x,
    const float* __restrict__ conv_w,
    const float* __restrict__ gamma,
    const float* __restrict__ beta,
    const float* __restrict__ mean,
    const float* __restrict__ var,
    const float* __restrict__ lamb_l,
    const float* __restrict__ lamb_h,
    const float* __restrict__ ia,
    float* __restrict__ out,
    float* __restrict__ ws)     // [0,1024): partials; [1024,2048): ready flags
{
    // Bijective XCD swizzle (1024 = 8 x 128): keep a plane's two blocks and
    // neighbors on one XCD so pool-read lines are in the SAME L2 the conv hits.
    const int bid  = (int)(blockIdx.x & 7) * 128 + (int)(blockIdx.x >> 3);
    const int wid  = threadIdx.x >> 6;          // wave 0..3
    const int lane = threadIdx.x & 63;
    const int nc   = bid >> 1;                  // plane 0..511
    const int half = bid & 1;                   // which 128-row half
    const int c    = nc & (CC - 1);
    const int n    = nc >> 6;
    const int g    = c >> 3;                    // C/G = 8

    const float* base    = x   + (size_t)nc * (HH * WW);
    float*       outbase = out + (size_t)nc * (HH * WW);
    int*         ready   = (int*)(ws + NBLK);

    // ---- phase 1: pool MY OWN conv region (128 rows), f4/lane ----
    float s = 0.f;
    {
        const int rbase = half * 128 + wid * 32;
#pragma unroll 8
        for (int i = 0; i < 32; ++i) {
            f4 v = ((const f4*)(base + (size_t)(rbase + i) * WW))[lane];
            s += (v.x + v.y) + (v.z + v.w);
        }
    }
    for (int off = 32; off > 0; off >>= 1) s += __shfl_down(s, off, 64);
    __shared__ float red[4];
    if (lane == 0) red[wid] = s;
    __syncthreads();
    if (threadIdx.x == 0) {
        float t = (red[0] + red[1]) + (red[2] + red[3]);
        ws[bid] = t;                                   // plain store...
        __hip_atomic_store(&ready[bid], 1, __ATOMIC_RELEASE,
                           __HIP_MEMORY_SCOPE_AGENT);  // ...ordered by release
    }

    // ---- hoist chunk-0 row loads: x-latency hides under spin + taps ----
    f4 v0[10];
    {
        const int r0 = half * 128 + wid * 8;
#pragma unroll
        for (int i = 0; i < 10; ++i) {
            int r = r0 - 1 + i;
            r = (r < 0) ? 1 : ((r > HH - 1) ? HH - 2 : r);   // reflection pad
            v0[i] = ((const f4*)(base + (size_t)r * WW))[lane];
        }
    }

    // ---- store-only sync: thread t waits for producer block n*128+t ----
    if (threadIdx.x < 128) {
        while (__hip_atomic_load(&ready[n * 128 + threadIdx.x], __ATOMIC_ACQUIRE,
                                 __HIP_MEMORY_SCOPE_AGENT) == 0) {
            __builtin_amdgcn_s_sleep(2);
        }
    }
    __syncthreads();

    // ---- phase 2: rebuild pooled row + this group's 9 taps ----
    __shared__ float part[128];
    __shared__ float pl[CC];
    __shared__ float lfs[K2];
    if (threadIdx.x < 128) part[threadIdx.x] = ws[n * 128 + threadIdx.x];
    __syncthreads();
    if (threadIdx.x < CC)
        pl[threadIdx.x] = (part[2 * threadIdx.x] + part[2 * threadIdx.x + 1])
                          * (1.0f / (HH * WW));
    __syncthreads();
    if (threadIdx.x < K2) {
        int oc = g * K2 + threadIdx.x;
        const float* pw = conv_w + oc * CC;
        float acc = 0.f;
#pragma unroll
        for (int cc2 = 0; cc2 < CC; ++cc2) acc += pl[cc2] * pw[cc2];
        float inv = gamma[oc] / sqrtf(var[oc] + BN_EPS);
        lfs[threadIdx.x] = tanhf((acc - mean[oc]) * inv + beta[oc]);
    }
    __syncthreads();

    const float w00 = lfs[0], w01 = lfs[1], w02 = lfs[2];
    const float w10 = lfs[3], w11 = lfs[4], w12 = lfs[5];
    const float w20 = lfs[6], w21 = lfs[7], w22 = lfs[8];
    const float ll    = lamb_l[c];
    const float lh1   = lamb_h[c] + 1.0f;
    const float iav   = ia[c];
    const float scale = iav + 1.0f;
    const float bias  = -iav * pl[c];

#define CONV_CHUNK(V, R0)                                                        \
    {                                                                            \
        float L[10], R[10];                                                      \
        _Pragma("unroll")                                                        \
        for (int i = 0; i < 10; ++i) {                                           \
            L[i] = __shfl_up(V[i].w, 1, 64);   if (lane == 0)  L[i] = V[i].y;    \
            R[i] = __shfl_down(V[i].x, 1, 64); if (lane == 63) R[i] = V[i].z;    \
        }                                                                        \
        _Pragma("unroll")                                                        \
        for (int j = 0; j < 8; ++j) {                                            \
            const float t[6]  = {L[j],   V[j].x,   V[j].y,   V[j].z,   V[j].w,   R[j]};   \
            const float m[6]  = {L[j+1], V[j+1].x, V[j+1].y, V[j+1].z, V[j+1].w, R[j+1]}; \
            const float bb[6] = {L[j+2], V[j+2].x, V[j+2].y, V[j+2].z, V[j+2].w, R[j+2]}; \
            f4 o;                                                                \
            _Pragma("unroll")                                                    \
            for (int k = 0; k < 4; ++k) {                                        \
                float acc = w00 * t[k]  + w01 * t[k + 1]  + w02 * t[k + 2]       \
                          + w10 * m[k]  + w11 * m[k + 1]  + w12 * m[k + 2]       \
                          + w20 * bb[k] + w21 * bb[k + 1] + w22 * bb[k + 2];     \
                o[k] = ll * (scale * acc + bias) + lh1 * m[k + 1];               \
            }                                                                    \
            __builtin_nontemporal_store(o, ((f4*)(outbase + (size_t)((R0) + j) * WW)) + lane); \
        }                                                                        \
    }

    // ---- phase 3: conv my 128 rows (4 chunks of 32; 8 rows/wave) ----
    CONV_CHUNK(v0, half * 128 + wid * 8)       // chunk 0: rows preloaded

    for (int chunk = 1; chunk < 4; ++chunk) {
        const int r0 = half * 128 + chunk * 32 + wid * 8;
        f4 v[10];
#pragma unroll
        for (int i = 0; i < 10; ++i) {
            int r = r0 - 1 + i;
            r = (r < 0) ? 1 : ((r > HH - 1) ? HH - 2 : r);
            v[i] = ((const f4*)(base + (size_t)r * WW))[lane];
        }
        CONV_CHUNK(v, r0)
    }
#undef CONV_CHUNK
}

extern "C" void kernel_launch(void* const* d_in, const int* in_sizes, int n_in,
                              void* d_out, int out_size, void* d_ws, size_t ws_size,
                              hipStream_t stream) {
    const float* x      = (const float*)d_in[0];
    const float* conv_w = (const float*)d_in[1];
    const float* gamma  = (const float*)d_in[2];
    const float* beta   = (const float*)d_in[3];
    const float* mean   = (const float*)d_in[4];
    const float* var    = (const float*)d_in[5];
    const float* lamb_l = (const float*)d_in[6];
    const float* lamb_h = (const float*)d_in[7];
    const float* ia     = (const float*)d_in[8];
    float* out = (float*)d_out;
    float* ws  = (float*)d_ws;     // 1024 partials + 1024 flags = 8 KiB

    hipMemsetAsync(ws, 0, 2 * NBLK * sizeof(float), stream);  // graph-safe
    fused_kernel<<<NBLK, 256, 0, stream>>>(x, conv_w, gamma, beta, mean, var,
                                           lamb_l, lamb_h, ia, out, ws);
}